// Round 10
// baseline (2978.240 us; speedup 1.0000x reference)
//
#include <hip/hip_runtime.h>

// ---------------------------------------------------------------------------
// <psi|U^dag O U|psi>, NQ=8, r=64 d=16 rl=16 ro=4.
// R10 = R9 + tiled intermediates: every tensor is stored as per-consumer-
// block contiguous panels so gemm staging is sequential uint4 streams
// (R9's 256KB-stride scalar gathers were the latency bottleneck: g45 pinned
// at 45us, MfmaUtil 27%, 930 GB/s).
// Formats (u32 = bf16 hi | lo<<16 split pair):
//   envT [(l,o,m2)·1024][a·64][b·64] f32      (16KB regions; G1/s7 read seq)
//   t1T  [(o,m2,a4)·1024][k=(l,i)·256][b·64] u32   (64KB regions, G2 reads)
//   t2T  [(L,m2,a4)·4096][k=(o,j)·64][b·64] f32    (16KB regions, G3 reads)
//   t3T  [(O2,L,a4)·1024][k=(m2,k2)·256][b·64] u32 (64KB regions, g45 reads)
// LDS: raw u32 tile [32][65] (pad65: stores/frag-reads <=2-way conflicts);
// fragment reads = 8x ds_read_b32 + unpack (R8-proven). Writers keep >=64B
// dense runs. gemm_g45 keeps R9's slab phase B. Numerics identical.
// ---------------------------------------------------------------------------

typedef __attribute__((ext_vector_type(8))) short bf16x8;
typedef __attribute__((ext_vector_type(4))) float f32x4;
typedef __attribute__((ext_vector_type(4))) unsigned short us4;

static __device__ __forceinline__ unsigned short f2bf(float x) {
    union { float f; unsigned u; } a; a.f = x;
    return (unsigned short)((a.u + 0x7FFF + ((a.u >> 16) & 1)) >> 16);
}
static __device__ __forceinline__ float bf2f(unsigned short h) {
    union { unsigned u; float f; } a; a.u = (unsigned)h << 16; return a.f;
}
static __device__ __forceinline__ unsigned split2(float x) {
    unsigned short h = f2bf(x);
    unsigned short l = f2bf(x - bf2f(h));
    return (unsigned)h | ((unsigned)l << 16);
}

__global__ void write_diag_kernel(float* out, float v) {
    if (threadIdx.x == 0 && blockIdx.x == 0) out[0] = v;
}
__global__ void zero_out(float* o) {
    if (threadIdx.x == 0 && blockIdx.x == 0) o[0] = 0.0f;
}

// ---- A-operand fragment packs (unchanged from R9) ------------------------
__global__ void prep_apack(const float* __restrict__ layer,
                           unsigned short* __restrict__ Ap2,
                           unsigned short* __restrict__ Ap4) {
    int idx = blockIdx.x * 256 + threadIdx.x;   // 65536
    int q = idx >> 13, k0 = (idx >> 10) & 7, mt = (idx >> 6) & 15, lane = idx & 63;
    int quad = lane >> 4, r = lane & 15;
    unsigned short h2[8], l2[8], h4[8], l4[8];
#pragma unroll
    for (int j = 0; j < 8; j++) {
        int k = k0 * 32 + quad * 8 + j;
        int m = mt * 16 + r;
        float v2 = layer[(size_t)q * 65536 +
                         (size_t)((((k >> 4) * 16 + (m >> 4)) * 16 + (k & 15)) * 16 + (m & 15))];
        float v4 = layer[(size_t)q * 65536 +
                         (size_t)((((k >> 4) * 16 + (k & 15)) * 16 + (m >> 4)) * 16 + (m & 15))];
        h2[j] = f2bf(v2); l2[j] = f2bf(v2 - bf2f(h2[j]));
        h4[j] = f2bf(v4); l4[j] = f2bf(v4 - bf2f(h4[j]));
    }
    size_t base = ((size_t)((q * 8 + k0) * 16 + mt) * 2) * 512 + lane * 8;
    *(us4*)(Ap2 + base)       = *(us4*)&h2[0];
    *(us4*)(Ap2 + base + 4)   = *(us4*)&h2[4];
    *(us4*)(Ap2 + base + 512) = *(us4*)&l2[0];
    *(us4*)(Ap2 + base + 516) = *(us4*)&l2[4];
    *(us4*)(Ap4 + base)       = *(us4*)&h4[0];
    *(us4*)(Ap4 + base + 4)   = *(us4*)&h4[4];
    *(us4*)(Ap4 + base + 512) = *(us4*)&l4[0];
    *(us4*)(Ap4 + base + 516) = *(us4*)&l4[4];
}

__global__ void prep_spack1(const float* __restrict__ state,
                            unsigned short* __restrict__ Sp1) {
    int idx = blockIdx.x * 256 + threadIdx.x;   // 65536
    int q = idx >> 13, c = (idx >> 11) & 3, k0 = (idx >> 10) & 1,
        mt = (idx >> 6) & 15, lane = idx & 63;
    int quad = lane >> 4, lr = lane & 15;
    unsigned short h[8], l[8];
#pragma unroll
    for (int j = 0; j < 8; j++) {
        int k = k0 * 32 + quad * 8 + j;
        float v = state[(size_t)q * 65536 + (size_t)(k * 16 + mt) * 64 + c * 16 + lr];
        h[j] = f2bf(v); l[j] = f2bf(v - bf2f(h[j]));
    }
    size_t base = (size_t)(q * 4 + c) * 32768 + ((size_t)(k0 * 16 + mt) * 2) * 512 + lane * 8;
    *(us4*)(Sp1 + base)       = *(us4*)&h[0];
    *(us4*)(Sp1 + base + 4)   = *(us4*)&h[4];
    *(us4*)(Sp1 + base + 512) = *(us4*)&l[0];
    *(us4*)(Sp1 + base + 516) = *(us4*)&l[4];
}

__global__ void prep_spack5(const float* __restrict__ state,
                            unsigned short* __restrict__ Sp5) {
    int idx = blockIdx.x * 256 + threadIdx.x;   // 65536
    int q = idx >> 13, k0 = (idx >> 8) & 31, mt = (idx >> 6) & 3, lane = idx & 63;
    int quad = lane >> 4, lr = lane & 15;
    unsigned short h[8], l[8];
#pragma unroll
    for (int j = 0; j < 8; j++) {
        int k = k0 * 32 + quad * 8 + j;   // k = s*64+b
        int s = k >> 6, b = k & 63;
        float v = state[(size_t)q * 65536 + (size_t)(b * 16 + s) * 64 + mt * 16 + lr];
        h[j] = f2bf(v); l[j] = f2bf(v - bf2f(h[j]));
    }
    size_t base = (size_t)q * 131072 + ((size_t)(k0 * 4 + mt) * 2) * 512 + lane * 8;
    *(us4*)(Sp5 + base)       = *(us4*)&h[0];
    *(us4*)(Sp5 + base + 4)   = *(us4*)&h[4];
    *(us4*)(Sp5 + base + 512) = *(us4*)&l[0];
    *(us4*)(Sp5 + base + 516) = *(us4*)&l[4];
}

__global__ void prep_opack3(const float* __restrict__ oper,
                            unsigned short* __restrict__ Op3) {
    int idx = blockIdx.x * 256 + threadIdx.x;   // 4096
    int q = idx >> 9, k0 = (idx >> 8) & 1, mt = (idx >> 6) & 3, lane = idx & 63;
    int quad = lane >> 4, lr = lane & 15;
    unsigned short h[8], l[8];
#pragma unroll
    for (int j = 0; j < 8; j++) {
        int k = k0 * 32 + quad * 8 + j;
        int m = mt * 16 + lr;
        float v = oper[(size_t)q * 4096 + (size_t)(k * 16 + (m >> 2)) * 4 + (m & 3)];
        h[j] = f2bf(v); l[j] = f2bf(v - bf2f(h[j]));
    }
    size_t base = (size_t)q * 8192 + ((size_t)(k0 * 4 + mt) * 2) * 512 + lane * 8;
    *(us4*)(Op3 + base)       = *(us4*)&h[0];
    *(us4*)(Op3 + base + 4)   = *(us4*)&h[4];
    *(us4*)(Op3 + base + 512) = *(us4*)&l[0];
    *(us4*)(Op3 + base + 516) = *(us4*)&l[4];
}

// ---- site 0 (env0 = delta): env1 built by a cheap chain (fp32 exact) ----
__global__ void s0_g2(const float* __restrict__ state, const float* __restrict__ layer,
                      float* __restrict__ g2) {
    int t = blockIdx.x * 256 + threadIdx.x;          // 16384: [A][j][L]
    int A = t >> 8, j = (t >> 4) & 15, L = t & 15;
    float s = 0;
    for (int i = 0; i < 16; i++) s += state[i * 64 + A] * layer[(j * 16 + i) * 16 + L];
    g2[t] = s;
}
__global__ void s0_g3(const float* __restrict__ g2, const float* __restrict__ oper,
                      float* __restrict__ g3) {
    int t = blockIdx.x * 256 + threadIdx.x;          // 65536: [A][L][k][O]
    int A = t >> 10, L = (t >> 6) & 15, k = (t >> 2) & 15, O = t & 3;
    float s = 0;
    for (int j = 0; j < 16; j++) s += g2[A * 256 + j * 16 + L] * oper[(j * 16 + k) * 4 + O];
    g3[t] = s;
}
__global__ void s0_g4(const float* __restrict__ g3, const float* __restrict__ layer,
                      float* __restrict__ g4) {
    int t = blockIdx.x * 256 + threadIdx.x;          // 1048576: [A][L][O][s][M]
    int A = t >> 14, L = (t >> 10) & 15, O = (t >> 8) & 3, sp = (t >> 4) & 15, M = t & 15;
    float s = 0;
    for (int k = 0; k < 16; k++)
        s += g3[A * 1024 + L * 64 + k * 4 + O] * layer[(k * 16 + sp) * 16 + M];
    g4[t] = s;
}
// envT[(L*64+O*16+M)·4096 + A*64 + B]; A block-uniform -> broadcast g4 reads
__global__ void s0_env(const float* __restrict__ g4, const float* __restrict__ state,
                       float* __restrict__ env) {
    int t = blockIdx.x * 256 + threadIdx.x;          // 4194304: [A][L][O][M][B]
    int A = t >> 16, L = (t >> 12) & 15, O = (t >> 10) & 3, M = (t >> 6) & 15, B = t & 63;
    float s = 0;
    for (int sp = 0; sp < 16; sp++)
        s += g4[A * 16384 + L * 1024 + O * 256 + sp * 16 + M] * state[sp * 64 + B];
    env[(size_t)(L * 64 + O * 16 + M) * 4096 + A * 64 + B] = s;
}

// ---- site 7 chain (fp32) + fused dot ------------------------------------
__global__ void s7_c1(const float* __restrict__ state, const float* __restrict__ layer,
                      float* __restrict__ c1) {
    int t = blockIdx.x * 256 + threadIdx.x;          // 16384: [l][a][j]
    int l = t >> 10, a = (t >> 4) & 63, j = t & 15;
    float s = 0;
    for (int i = 0; i < 16; i++)
        s += state[7 * 65536 + (a * 16 + i) * 64] * layer[7 * 65536 + ((l * 16 + j) * 16 + i) * 16];
    c1[t] = s;
}
__global__ void s7_c2(const float* __restrict__ c1, const float* __restrict__ oper,
                      float* __restrict__ c2) {
    int t = blockIdx.x * 256 + threadIdx.x;          // 65536: [o][l][a][k]
    int o = t >> 14, l = (t >> 10) & 15, a = (t >> 4) & 63, k = t & 15;
    float s = 0;
    for (int j = 0; j < 16; j++)
        s += c1[l * 1024 + a * 16 + j] * oper[7 * 4096 + ((o * 16 + j) * 16 + k) * 4];
    c2[t] = s;
}
__global__ void s7_c3(const float* __restrict__ c2, const float* __restrict__ layer,
                      float* __restrict__ c3) {
    int t = blockIdx.x * 256 + threadIdx.x;          // 1048576: [m][o][l][a][s]
    int m = t >> 16, o = (t >> 14) & 3, l = (t >> 10) & 15, a = (t >> 4) & 63, sp = t & 15;
    float s = 0;
    for (int k = 0; k < 16; k++)
        s += c2[o * 16384 + l * 1024 + a * 16 + k] *
             layer[7 * 65536 + ((m * 16 + k) * 16 + sp) * 16];
    c3[t] = s;
}
__global__ void prep_sv(const float* __restrict__ state, float* __restrict__ sv) {
    int t = blockIdx.x * 256 + threadIdx.x;          // 1024: [b][sp]
    sv[t] = state[7 * 65536 + t * 64];
}
__global__ __launch_bounds__(256) void s7_fused(const float* __restrict__ env,
                                                const float* __restrict__ c3,
                                                const float* __restrict__ sv,
                                                float* __restrict__ out) {
    __shared__ float c3s[1024], svs[1024], red[256];
    int t = threadIdx.x;
    int n0 = blockIdx.x * 64;            // 1024 blocks; region=(l,o,m)
    int l = n0 >> 12, o = (n0 >> 10) & 3, m = (n0 >> 6) & 15;
    const float* c3b = c3 + m * 65536 + o * 16384 + l * 1024;   // [a][sp]
    const float* eb  = env + (size_t)blockIdx.x * 4096;         // [a][b]
    for (int i = t; i < 1024; i += 256) { c3s[i] = c3b[i]; svs[i] = sv[i]; }
    __syncthreads();
    float s = 0;
    int b = t & 63, ag = t >> 6;
#pragma unroll
    for (int g = 0; g < 16; g++) {
        int a = ag * 16 + g;
        float e = eb[a * 64 + b];
        float w = 0;
#pragma unroll
        for (int sp = 0; sp < 16; sp++) w += c3s[a * 16 + sp] * svs[b * 16 + sp];
        s += e * w;
    }
    red[t] = s; __syncthreads();
    for (int off = 128; off; off >>= 1) { if (t < off) red[t] += red[t + off]; __syncthreads(); }
    if (t == 0) atomicAdd(out, red[0]);
}

// ---- unified bf16x3 MFMA GEMM (G1 / G2 / G3), tiled-panel inputs ---------
// B region = blockIdx.x panel of KT*2048 elems; tile k0 = contiguous 8KB.
// LDS: raw 32x65 u32 tile. Fragments: 8x ds_read_b32 + unpack.
// BFMT=0: u32 split-pair panel; BFMT=1: f32 panel (split on fragment read).
template <int KT, int MT, int WS, int BFMT, int SM>
__global__ __launch_bounds__(256) void gemm_u(const unsigned* __restrict__ Bv,
                                              const unsigned short* __restrict__ Ap,
                                              float* __restrict__ Cf,
                                              unsigned* __restrict__ Cu) {
    constexpr int NT = (WS == 0) ? 4 : 1;
    __shared__ unsigned Bt[32 * 65];
    const int tid = threadIdx.x, lane = tid & 63, wave = tid >> 6;
    const int quad = lane >> 4, lr = lane & 15;

    f32x4 acc[4][NT];
#pragma unroll
    for (int i = 0; i < 4; i++)
#pragma unroll
        for (int j = 0; j < NT; j++)
#pragma unroll
            for (int r = 0; r < 4; r++) acc[i][j][r] = 0.0f;

    uint4 ur[2];
    auto load_tile = [&](int k0) {
        const uint4* src = (const uint4*)(Bv + (size_t)blockIdx.x * (KT * 2048) + k0 * 2048);
        ur[0] = src[tid];
        ur[1] = src[256 + tid];
    };
    auto store_tile = [&]() {
#pragma unroll
        for (int v = 0; v < 2; v++) {
            int e = v * 256 + tid;
            unsigned* p = &Bt[(e >> 4) * 65 + (e & 15) * 4];
            p[0] = ur[v].x; p[1] = ur[v].y; p[2] = ur[v].z; p[3] = ur[v].w;
        }
    };

    load_tile(0);
    store_tile();
    for (int k0 = 0; k0 < KT; k0++) {
        __syncthreads();
        if (k0 + 1 < KT) load_tile(k0 + 1);
        bf16x8 ah[4], al[4];
#pragma unroll
        for (int mt = 0; mt < 4; mt++) {
            int gmt = (WS == 0) ? (wave * 4 + mt) : mt;
            const unsigned short* ap = Ap + ((size_t)(k0 * MT + gmt) * 2) * 512 + lane * 8;
            ah[mt] = *(const bf16x8*)ap;
            al[mt] = *(const bf16x8*)(ap + 512);
        }
#pragma unroll
        for (int nt = 0; nt < NT; nt++) {
            int nl = (WS == 0) ? (nt * 16 + lr) : (wave * 16 + lr);
            bf16x8 bh, bl;
#pragma unroll
            for (int j = 0; j < 8; j++) {
                unsigned u = Bt[(quad * 8 + j) * 65 + nl];
                if constexpr (BFMT == 0) {
                    bh[j] = (short)(u & 0xffff);
                    bl[j] = (short)(u >> 16);
                } else {
                    union { unsigned uu; float ff; } c; c.uu = u;
                    unsigned short hh = f2bf(c.ff);
                    bh[j] = (short)hh;
                    bl[j] = (short)f2bf(c.ff - bf2f(hh));
                }
            }
#pragma unroll
            for (int mt = 0; mt < 4; mt++) {
                acc[mt][nt] = __builtin_amdgcn_mfma_f32_16x16x32_bf16(ah[mt], bh, acc[mt][nt], 0, 0, 0);
                acc[mt][nt] = __builtin_amdgcn_mfma_f32_16x16x32_bf16(ah[mt], bl, acc[mt][nt], 0, 0, 0);
                acc[mt][nt] = __builtin_amdgcn_mfma_f32_16x16x32_bf16(al[mt], bh, acc[mt][nt], 0, 0, 0);
            }
        }
        __syncthreads();
        if (k0 + 1 < KT) store_tile();
    }

    // epilogues: block-region decode per stage
#pragma unroll
    for (int mt = 0; mt < 4; mt++) {
        int gmt = (WS == 0) ? (wave * 4 + mt) : mt;
#pragma unroll
        for (int nt = 0; nt < NT; nt++) {
            int b = (WS == 0) ? (nt * 16 + lr) : (wave * 16 + lr);
#pragma unroll
            for (int r = 0; r < 4; r++) {
                int m = gmt * 16 + quad * 4 + r;
                float val = acc[mt][nt][r];
                if constexpr (SM == 1) {
                    // region=(l,o,m2); m=(i,a4) -> t1T[(o,m2,a4)][l*16+i][b]
                    int l = blockIdx.x >> 6, o = (blockIdx.x >> 4) & 3, m2 = blockIdx.x & 15;
                    Cu[(size_t)((o * 256 + m2 * 16 + (m & 15))) * 16384 +
                       (l * 16 + (m >> 4)) * 64 + b] = split2(val);
                } else if constexpr (SM == 2) {
                    // region=(o,m2,a4); m=(j,L) -> t2T[(L,m2,a4)][o*16+j][b]
                    int o = blockIdx.x >> 8, m2 = (blockIdx.x >> 4) & 15, a4 = blockIdx.x & 15;
                    Cf[(size_t)((m & 15) * 256 + m2 * 16 + a4) * 4096 +
                       (o * 16 + (m >> 4)) * 64 + b] = val;
                } else {
                    // SM==3: region=(L,m2,a4); m=(k2,O2) -> t3T[(O2,L,a4)][m2*16+k2][b]
                    int L = blockIdx.x >> 8, m2 = (blockIdx.x >> 4) & 15, a4 = blockIdx.x & 15;
                    Cu[(size_t)((m & 3) * 256 + L * 16 + a4) * 16384 +
                       (m2 * 16 + (m >> 2)) * 64 + b] = split2(val);
                }
            }
        }
    }
}

// ---- fused G4+G5 (tiled t3 in, slab phase B, tiled env out) --------------
__global__ __launch_bounds__(256) void gemm_g45(const unsigned* __restrict__ Bp,
                                                const unsigned short* __restrict__ Ap4,
                                                const unsigned short* __restrict__ Sp5,
                                                float* __restrict__ env, int A0) {
    __shared__ unsigned Bt[32 * 65];
    __shared__ unsigned short S_h[16 * 264];
    __shared__ unsigned short S_l[16 * 264];
    const int tid = threadIdx.x, lane = tid & 63, wave = tid >> 6;
    const int quad = lane >> 4, lr = lane & 15;
    const int O2 = blockIdx.x >> 8, L = (blockIdx.x >> 4) & 15, a4 = blockIdx.x & 15;

    f32x4 acc[4][4];
#pragma unroll
    for (int i = 0; i < 4; i++)
#pragma unroll
        for (int j = 0; j < 4; j++)
#pragma unroll
            for (int r = 0; r < 4; r++) acc[i][j][r] = 0.0f;

    uint4 ur[2];
    auto load_tile = [&](int k0) {
        const uint4* src = (const uint4*)(Bp + (size_t)blockIdx.x * 16384 + k0 * 2048);
        ur[0] = src[tid];
        ur[1] = src[256 + tid];
    };
    auto store_tile = [&]() {
#pragma unroll
        for (int v = 0; v < 2; v++) {
            int e = v * 256 + tid;
            unsigned* p = &Bt[(e >> 4) * 65 + (e & 15) * 4];
            p[0] = ur[v].x; p[1] = ur[v].y; p[2] = ur[v].z; p[3] = ur[v].w;
        }
    };

    load_tile(0);
    store_tile();
    for (int k0 = 0; k0 < 8; k0++) {
        __syncthreads();
        if (k0 + 1 < 8) load_tile(k0 + 1);
        bf16x8 ah[4], al[4];
#pragma unroll
        for (int mt = 0; mt < 4; mt++) {
            const unsigned short* ap =
                Ap4 + ((size_t)(k0 * 16 + wave * 4 + mt) * 2) * 512 + lane * 8;
            ah[mt] = *(const bf16x8*)ap;
            al[mt] = *(const bf16x8*)(ap + 512);
        }
#pragma unroll
        for (int nt = 0; nt < 4; nt++) {
            int nl = nt * 16 + lr;
            bf16x8 bh, bl;
#pragma unroll
            for (int j = 0; j < 8; j++) {
                unsigned u = Bt[(quad * 8 + j) * 65 + nl];
                bh[j] = (short)(u & 0xffff);
                bl[j] = (short)(u >> 16);
            }
#pragma unroll
            for (int mt = 0; mt < 4; mt++) {
                acc[mt][nt] = __builtin_amdgcn_mfma_f32_16x16x32_bf16(ah[mt], bh, acc[mt][nt], 0, 0, 0);
                acc[mt][nt] = __builtin_amdgcn_mfma_f32_16x16x32_bf16(ah[mt], bl, acc[mt][nt], 0, 0, 0);
                acc[mt][nt] = __builtin_amdgcn_mfma_f32_16x16x32_bf16(al[mt], bh, acc[mt][nt], 0, 0, 0);
            }
        }
        __syncthreads();
        if (k0 + 1 < 8) store_tile();
    }

    // phase B: per mt, deposit slab (s = wave*4+mt; k-local = wave*64+b) then
    // contract k-chunks (s2,h): global chunk = (s2*4+mt)*2+h, local = s2*64+h*32
    f32x4 acc5;
#pragma unroll
    for (int r = 0; r < 4; r++) acc5[r] = 0.0f;
#pragma unroll
    for (int mt = 0; mt < 4; mt++) {
        if (mt) __syncthreads();
#pragma unroll
        for (int nt = 0; nt < 4; nt++)
#pragma unroll
            for (int r = 0; r < 4; r++) {
                unsigned u = split2(acc[mt][nt][r]);
                int addr = (quad * 4 + r) * 264 + wave * 64 + nt * 16 + lr;
                S_h[addr] = (unsigned short)u;
                S_l[addr] = (unsigned short)(u >> 16);
            }
        __syncthreads();
#pragma unroll
        for (int s2 = 0; s2 < 4; s2++)
#pragma unroll
            for (int h = 0; h < 2; h++) {
                int klocal = s2 * 64 + h * 32;
                bf16x8 th = *(const bf16x8*)(&S_h[lr * 264 + klocal + quad * 8]);
                bf16x8 tl = *(const bf16x8*)(&S_l[lr * 264 + klocal + quad * 8]);
                int kg = (s2 * 4 + mt) * 2 + h;
                const unsigned short* bp =
                    Sp5 + ((size_t)(kg * 4 + wave) * 2) * 512 + lane * 8;
                bf16x8 sh = *(const bf16x8*)bp;
                bf16x8 sl = *(const bf16x8*)(bp + 512);
                acc5 = __builtin_amdgcn_mfma_f32_16x16x32_bf16(th, sh, acc5, 0, 0, 0);
                acc5 = __builtin_amdgcn_mfma_f32_16x16x32_bf16(th, sl, acc5, 0, 0, 0);
                acc5 = __builtin_amdgcn_mfma_f32_16x16x32_bf16(tl, sh, acc5, 0, 0, 0);
            }
    }
    // row=M2=quad*4+r, col=B'=wave*16+lr -> envT[(L*64+O2*16+M2)][A0+a4][B']
#pragma unroll
    for (int r = 0; r < 4; r++)
        env[(size_t)(L * 64 + O2 * 16 + quad * 4 + r) * 4096 +
            (A0 + a4) * 64 + wave * 16 + lr] = acc5[r];
}

extern "C" void kernel_launch(void* const* d_in, const int* in_sizes, int n_in,
                              void* d_out, int out_size, void* d_ws, size_t ws_size,
                              hipStream_t stream) {
    const float* state = (const float*)d_in[0];   // [8,64,16,64]
    const float* layer = (const float*)d_in[1];   // [1,8,16,16,16,16]
    const float* oper  = (const float*)d_in[2];   // [8,4,16,16,4]
    float* out = (float*)d_out;

    const size_t need = (16777216ull + 16777216ull + 2 * 4194304ull) * 4ull +
                        (4 * 1048576ull + 65536ull) * 2ull + 4096ull;
    if (ws_size < need) {
        write_diag_kernel<<<1, 64, 0, stream>>>(out, (float)ws_size);
        return;
    }
    float* F    = (float*)d_ws;                    // t2T (also boundary scratch)
    unsigned* P = (unsigned*)(F + 16777216);       // t1T / t3T
    float* envA = (float*)(P + 16777216);
    float* envB = envA + 4194304;
    unsigned short* Ap2 = (unsigned short*)(envB + 4194304);
    unsigned short* Ap4 = Ap2 + 1048576;
    unsigned short* Sp1 = Ap4 + 1048576;
    unsigned short* Sp5 = Sp1 + 1048576;
    unsigned short* Op3 = Sp5 + 1048576;
    float* sv = (float*)(Op3 + 65536);
    float* SCR = F;

    prep_apack<<<256, 256, 0, stream>>>(layer, Ap2, Ap4);
    prep_spack1<<<256, 256, 0, stream>>>(state, Sp1);
    prep_spack5<<<256, 256, 0, stream>>>(state, Sp5);
    prep_opack3<<<16, 256, 0, stream>>>(oper, Op3);
    prep_sv<<<4, 256, 0, stream>>>(state, sv);

    // site 0 -> envB (exact fp32), envT tiled
    s0_g2<<<64, 256, 0, stream>>>(state, layer, SCR);
    s0_g3<<<256, 256, 0, stream>>>(SCR, oper, SCR + 16384);
    s0_g4<<<4096, 256, 0, stream>>>(SCR + 16384, layer, SCR + 81920);
    s0_env<<<16384, 256, 0, stream>>>(SCR + 81920, state, envB);

    for (int q = 1; q < 7; q++) {
        float* ein  = (q & 1) ? envB : envA;
        float* eout = (q & 1) ? envA : envB;
        for (int c = 0; c < 4; c++) {
            // G1: envT f32 panels x Sp1 -> t1T u32 panels
            gemm_u<2, 16, 0, 1, 1><<<1024, 256, 0, stream>>>(
                (const unsigned*)ein, Sp1 + (size_t)(q * 4 + c) * 32768, nullptr, P);
            // G2: t1T u32 panels x Ap2 -> t2T f32 panels
            gemm_u<8, 16, 0, 0, 2><<<1024, 256, 0, stream>>>(
                P, Ap2 + (size_t)q * 131072, F, nullptr);
            // G3: t2T f32 panels x Op3 -> t3T u32 panels
            gemm_u<2, 4, 1, 1, 3><<<4096, 256, 0, stream>>>(
                (const unsigned*)F, Op3 + (size_t)q * 8192, nullptr, P);
            // G4+G5 fused: t3T panels x Ap4 -> (LDS t4) x Sp5 -> envT slice
            gemm_g45<<<1024, 256, 0, stream>>>(
                P, Ap4 + (size_t)q * 131072, Sp5 + (size_t)q * 131072, eout, c * 16);
        }
    }

    // site 7: out = <env7 (envT, in envB), w>
    s7_c1<<<64, 256, 0, stream>>>(state, layer, SCR);
    s7_c2<<<256, 256, 0, stream>>>(SCR, oper, SCR + 16384);
    s7_c3<<<4096, 256, 0, stream>>>(SCR + 16384, layer, SCR + 81920);
    zero_out<<<1, 64, 0, stream>>>(out);
    s7_fused<<<1024, 256, 0, stream>>>(envB, SCR + 81920, sv, out);
}

// Round 11
// 1909.116 us; speedup vs baseline: 1.5600x; 1.5600x over previous
//
#include <hip/hip_runtime.h>

// ---------------------------------------------------------------------------
// <psi|U^dag O U|psi>, NQ=8, r=64 d=16 rl=16 ro=4.
// R11: intermediates t1/t2/t3 in f16 (half traffic) with exact power-of-2
// per-site scaling (t1 *= 2^(16+2q), inherited by t2/t3/t4, removed at env'
// write). G2/G3/g45-phaseA are LDS-free: producers write k-blocked panels
// [region][k/8][b][k%8] so B-fragments are direct coalesced 16B global loads,
// double-buffered in registers -> no __syncthreads in the K-loop. 1 f16 MFMA
// per (mt,nt) (A hi-only f16; quantization budget ~0.12% RMS vs 2% threshold).
// G1 keeps the proven bf16x3 LDS path (B = env fp32); g45 phase B keeps the
// bf16 slab path. Boundary sites 0/7 fp32 exact.
// Formats:
//   envT [(l,o,m2)·1024][a·64][b·64] f32 (unscaled)
//   t1   [(o,m2,a4)·1024][k2=(l,i)/8][b·64][k2%8] f16   (32 MB)
//   t2   [(L,m2,a4)·4096][k3=(o,j)/8][b·64][k3%8] f16   (32 MB)
//   t3   [(O2,L,a4)·1024][k4=(m2,k2)/8][b·64][k4%8] f16 (32 MB)
// ---------------------------------------------------------------------------

typedef __attribute__((ext_vector_type(8))) short bf16x8;
typedef __attribute__((ext_vector_type(8))) _Float16 f16x8;
typedef __attribute__((ext_vector_type(4))) float f32x4;
typedef __attribute__((ext_vector_type(4))) unsigned short us4;

static __device__ __forceinline__ unsigned short f2bf(float x) {
    union { float f; unsigned u; } a; a.f = x;
    return (unsigned short)((a.u + 0x7FFF + ((a.u >> 16) & 1)) >> 16);
}
static __device__ __forceinline__ float bf2f(unsigned short h) {
    union { unsigned u; float f; } a; a.u = (unsigned)h << 16; return a.f;
}
static __device__ __forceinline__ unsigned split2(float x) {
    unsigned short h = f2bf(x);
    unsigned short l = f2bf(x - bf2f(h));
    return (unsigned)h | ((unsigned)l << 16);
}
static __device__ __forceinline__ unsigned short f2h_bits(float x) {
    union { _Float16 h; unsigned short u; } c; c.h = (_Float16)x; return c.u;
}
static __device__ __forceinline__ float h2f_bits(unsigned short u) {
    union { unsigned short u; _Float16 h; } c; c.u = u; return (float)c.h;
}

__global__ void write_diag_kernel(float* out, float v) {
    if (threadIdx.x == 0 && blockIdx.x == 0) out[0] = v;
}
__global__ void zero_out(float* o) {
    if (threadIdx.x == 0 && blockIdx.x == 0) o[0] = 0.0f;
}

// ---- A-operand fragment packs -------------------------------------------
// Pack layout: [(k0*MT+mt)*2+hl][lane(64)][8]; frag k = k0*32+quad*8+j,
// m = mt*16 + (lane&15).

// G2 (Ud, k=(l,i), m=(j,L)) / G4 (U, k=(m2,k2), m=(s,M2)); f16 pair; MT=16
__global__ void prep_apack(const float* __restrict__ layer,
                           unsigned short* __restrict__ Ap2,
                           unsigned short* __restrict__ Ap4) {
    int idx = blockIdx.x * 256 + threadIdx.x;   // 65536
    int q = idx >> 13, k0 = (idx >> 10) & 7, mt = (idx >> 6) & 15, lane = idx & 63;
    int quad = lane >> 4, r = lane & 15;
    unsigned short h2[8], l2[8], h4[8], l4[8];
#pragma unroll
    for (int j = 0; j < 8; j++) {
        int k = k0 * 32 + quad * 8 + j;
        int m = mt * 16 + r;
        float v2 = layer[(size_t)q * 65536 +
                         (size_t)((((k >> 4) * 16 + (m >> 4)) * 16 + (k & 15)) * 16 + (m & 15))];
        float v4 = layer[(size_t)q * 65536 +
                         (size_t)((((k >> 4) * 16 + (k & 15)) * 16 + (m >> 4)) * 16 + (m & 15))];
        h2[j] = f2h_bits(v2); l2[j] = f2h_bits(v2 - h2f_bits(h2[j]));
        h4[j] = f2h_bits(v4); l4[j] = f2h_bits(v4 - h2f_bits(h4[j]));
    }
    size_t base = ((size_t)((q * 8 + k0) * 16 + mt) * 2) * 512 + lane * 8;
    *(us4*)(Ap2 + base)       = *(us4*)&h2[0];
    *(us4*)(Ap2 + base + 4)   = *(us4*)&h2[4];
    *(us4*)(Ap2 + base + 512) = *(us4*)&l2[0];
    *(us4*)(Ap2 + base + 516) = *(us4*)&l2[4];
    *(us4*)(Ap4 + base)       = *(us4*)&h4[0];
    *(us4*)(Ap4 + base + 4)   = *(us4*)&h4[4];
    *(us4*)(Ap4 + base + 512) = *(us4*)&l4[0];
    *(us4*)(Ap4 + base + 516) = *(us4*)&l4[4];
}

// G1 (S as A, bf16 pair): Amat[k=a][m=(i,a4)] = state[q][a][i][c*16+a4]; MT=16
__global__ void prep_spack1(const float* __restrict__ state,
                            unsigned short* __restrict__ Sp1) {
    int idx = blockIdx.x * 256 + threadIdx.x;   // 65536
    int q = idx >> 13, c = (idx >> 11) & 3, k0 = (idx >> 10) & 1,
        mt = (idx >> 6) & 15, lane = idx & 63;
    int quad = lane >> 4, lr = lane & 15;
    unsigned short h[8], l[8];
#pragma unroll
    for (int j = 0; j < 8; j++) {
        int k = k0 * 32 + quad * 8 + j;
        float v = state[(size_t)q * 65536 + (size_t)(k * 16 + mt) * 64 + c * 16 + lr];
        h[j] = f2bf(v); l[j] = f2bf(v - bf2f(h[j]));
    }
    size_t base = (size_t)(q * 4 + c) * 32768 + ((size_t)(k0 * 16 + mt) * 2) * 512 + lane * 8;
    *(us4*)(Sp1 + base)       = *(us4*)&h[0];
    *(us4*)(Sp1 + base + 4)   = *(us4*)&h[4];
    *(us4*)(Sp1 + base + 512) = *(us4*)&l[0];
    *(us4*)(Sp1 + base + 516) = *(us4*)&l[4];
}

// G5 (S, bf16 pair): frag[k=(s,b)=s*64+b][col=B'] = state[q][b][s][B']; MT=4
__global__ void prep_spack5(const float* __restrict__ state,
                            unsigned short* __restrict__ Sp5) {
    int idx = blockIdx.x * 256 + threadIdx.x;   // 65536
    int q = idx >> 13, k0 = (idx >> 8) & 31, mt = (idx >> 6) & 3, lane = idx & 63;
    int quad = lane >> 4, lr = lane & 15;
    unsigned short h[8], l[8];
#pragma unroll
    for (int j = 0; j < 8; j++) {
        int k = k0 * 32 + quad * 8 + j;   // k = s*64+b
        int s = k >> 6, b = k & 63;
        float v = state[(size_t)q * 65536 + (size_t)(b * 16 + s) * 64 + mt * 16 + lr];
        h[j] = f2bf(v); l[j] = f2bf(v - bf2f(h[j]));
    }
    size_t base = (size_t)q * 131072 + ((size_t)(k0 * 4 + mt) * 2) * 512 + lane * 8;
    *(us4*)(Sp5 + base)       = *(us4*)&h[0];
    *(us4*)(Sp5 + base + 4)   = *(us4*)&h[4];
    *(us4*)(Sp5 + base + 512) = *(us4*)&l[0];
    *(us4*)(Sp5 + base + 516) = *(us4*)&l[4];
}

// G3 (O as A, f16 pair): NEW m-mapping m=(O2,k2): Amat[k=(o,j2)][m] =
// oper[q][o][j2][k2=m&15][O2=m>>4]; MT=4
__global__ void prep_opack3(const float* __restrict__ oper,
                            unsigned short* __restrict__ Op3) {
    int idx = blockIdx.x * 256 + threadIdx.x;   // 4096
    int q = idx >> 9, k0 = (idx >> 8) & 1, mt = (idx >> 6) & 3, lane = idx & 63;
    int quad = lane >> 4, lr = lane & 15;
    unsigned short h[8], l[8];
#pragma unroll
    for (int j = 0; j < 8; j++) {
        int k = k0 * 32 + quad * 8 + j;
        int m = mt * 16 + lr;
        float v = oper[(size_t)q * 4096 + (size_t)(k * 16 + (m & 15)) * 4 + (m >> 4)];
        h[j] = f2h_bits(v); l[j] = f2h_bits(v - h2f_bits(h[j]));
    }
    size_t base = (size_t)q * 8192 + ((size_t)(k0 * 4 + mt) * 2) * 512 + lane * 8;
    *(us4*)(Op3 + base)       = *(us4*)&h[0];
    *(us4*)(Op3 + base + 4)   = *(us4*)&h[4];
    *(us4*)(Op3 + base + 512) = *(us4*)&l[0];
    *(us4*)(Op3 + base + 516) = *(us4*)&l[4];
}

// ---- site 0 (env0 = delta): env1 built by a cheap chain (fp32 exact) ----
__global__ void s0_g2(const float* __restrict__ state, const float* __restrict__ layer,
                      float* __restrict__ g2) {
    int t = blockIdx.x * 256 + threadIdx.x;          // 16384: [A][j][L]
    int A = t >> 8, j = (t >> 4) & 15, L = t & 15;
    float s = 0;
    for (int i = 0; i < 16; i++) s += state[i * 64 + A] * layer[(j * 16 + i) * 16 + L];
    g2[t] = s;
}
__global__ void s0_g3(const float* __restrict__ g2, const float* __restrict__ oper,
                      float* __restrict__ g3) {
    int t = blockIdx.x * 256 + threadIdx.x;          // 65536: [A][L][k][O]
    int A = t >> 10, L = (t >> 6) & 15, k = (t >> 2) & 15, O = t & 3;
    float s = 0;
    for (int j = 0; j < 16; j++) s += g2[A * 256 + j * 16 + L] * oper[(j * 16 + k) * 4 + O];
    g3[t] = s;
}
__global__ void s0_g4(const float* __restrict__ g3, const float* __restrict__ layer,
                      float* __restrict__ g4) {
    int t = blockIdx.x * 256 + threadIdx.x;          // 1048576: [A][L][O][s][M]
    int A = t >> 14, L = (t >> 10) & 15, O = (t >> 8) & 3, sp = (t >> 4) & 15, M = t & 15;
    float s = 0;
    for (int k = 0; k < 16; k++)
        s += g3[A * 1024 + L * 64 + k * 4 + O] * layer[(k * 16 + sp) * 16 + M];
    g4[t] = s;
}
// envT[(L*64+O*16+M)*4096 + A*64 + B]
__global__ void s0_env(const float* __restrict__ g4, const float* __restrict__ state,
                       float* __restrict__ env) {
    int t = blockIdx.x * 256 + threadIdx.x;          // 4194304
    int A = t >> 16, L = (t >> 12) & 15, O = (t >> 10) & 3, M = (t >> 6) & 15, B = t & 63;
    float s = 0;
    for (int sp = 0; sp < 16; sp++)
        s += g4[A * 16384 + L * 1024 + O * 256 + sp * 16 + M] * state[sp * 64 + B];
    env[(size_t)(L * 64 + O * 16 + M) * 4096 + A * 64 + B] = s;
}

// ---- site 7 chain (fp32) + fused dot ------------------------------------
__global__ void s7_c1(const float* __restrict__ state, const float* __restrict__ layer,
                      float* __restrict__ c1) {
    int t = blockIdx.x * 256 + threadIdx.x;          // 16384: [l][a][j]
    int l = t >> 10, a = (t >> 4) & 63, j = t & 15;
    float s = 0;
    for (int i = 0; i < 16; i++)
        s += state[7 * 65536 + (a * 16 + i) * 64] * layer[7 * 65536 + ((l * 16 + j) * 16 + i) * 16];
    c1[t] = s;
}
__global__ void s7_c2(const float* __restrict__ c1, const float* __restrict__ oper,
                      float* __restrict__ c2) {
    int t = blockIdx.x * 256 + threadIdx.x;          // 65536: [o][l][a][k]
    int o = t >> 14, l = (t >> 10) & 15, a = (t >> 4) & 63, k = t & 15;
    float s = 0;
    for (int j = 0; j < 16; j++)
        s += c1[l * 1024 + a * 16 + j] * oper[7 * 4096 + ((o * 16 + j) * 16 + k) * 4];
    c2[t] = s;
}
__global__ void s7_c3(const float* __restrict__ c2, const float* __restrict__ layer,
                      float* __restrict__ c3) {
    int t = blockIdx.x * 256 + threadIdx.x;          // 1048576: [m][o][l][a][s]
    int m = t >> 16, o = (t >> 14) & 3, l = (t >> 10) & 15, a = (t >> 4) & 63, sp = t & 15;
    float s = 0;
    for (int k = 0; k < 16; k++)
        s += c2[o * 16384 + l * 1024 + a * 16 + k] *
             layer[7 * 65536 + ((m * 16 + k) * 16 + sp) * 16];
    c3[t] = s;
}
__global__ void prep_sv(const float* __restrict__ state, float* __restrict__ sv) {
    int t = blockIdx.x * 256 + threadIdx.x;          // 1024: [b][sp]
    sv[t] = state[7 * 65536 + t * 64];
}
__global__ __launch_bounds__(256) void s7_fused(const float* __restrict__ env,
                                                const float* __restrict__ c3,
                                                const float* __restrict__ sv,
                                                float* __restrict__ out) {
    __shared__ float c3s[1024], svs[1024], red[256];
    int t = threadIdx.x;
    int n0 = blockIdx.x * 64;            // region=(l,o,m)
    int l = n0 >> 12, o = (n0 >> 10) & 3, m = (n0 >> 6) & 15;
    const float* c3b = c3 + m * 65536 + o * 16384 + l * 1024;   // [a][sp]
    const float* eb  = env + (size_t)blockIdx.x * 4096;         // [a][b]
    for (int i = t; i < 1024; i += 256) { c3s[i] = c3b[i]; svs[i] = sv[i]; }
    __syncthreads();
    float s = 0;
    int b = t & 63, ag = t >> 6;
#pragma unroll
    for (int g = 0; g < 16; g++) {
        int a = ag * 16 + g;
        float e = eb[a * 64 + b];
        float w = 0;
#pragma unroll
        for (int sp = 0; sp < 16; sp++) w += c3s[a * 16 + sp] * svs[b * 16 + sp];
        s += e * w;
    }
    red[t] = s; __syncthreads();
    for (int off = 128; off; off >>= 1) { if (t < off) red[t] += red[t + off]; __syncthreads(); }
    if (t == 0) atomicAdd(out, red[0]);
}

// ---- G1: env (fp32, LDS bf16x3) x Sp1 -> t1 f16 blocked panels -----------
__global__ __launch_bounds__(256) void gemm_g1(const float* __restrict__ envp,
                                               const unsigned short* __restrict__ Sp1,
                                               unsigned short* __restrict__ t1,
                                               float scale) {
    __shared__ unsigned Bt[32 * 65];
    const int tid = threadIdx.x, lane = tid & 63, wave = tid >> 6;
    const int quad = lane >> 4, lr = lane & 15;
    const int l = blockIdx.x >> 6, o = (blockIdx.x >> 4) & 3, m2 = blockIdx.x & 15;

    f32x4 acc[4][4];
#pragma unroll
    for (int i = 0; i < 4; i++)
#pragma unroll
        for (int j = 0; j < 4; j++)
#pragma unroll
            for (int r = 0; r < 4; r++) acc[i][j][r] = 0.0f;

    const unsigned* Bv = (const unsigned*)envp + (size_t)blockIdx.x * 4096;
    uint4 ur[2];
    auto load_tile = [&](int k0) {
        const uint4* src = (const uint4*)(Bv + k0 * 2048);
        ur[0] = src[tid];
        ur[1] = src[256 + tid];
    };
    auto store_tile = [&]() {
#pragma unroll
        for (int v = 0; v < 2; v++) {
            int e = v * 256 + tid;
            unsigned* p = &Bt[(e >> 4) * 65 + (e & 15) * 4];
            p[0] = ur[v].x; p[1] = ur[v].y; p[2] = ur[v].z; p[3] = ur[v].w;
        }
    };

    load_tile(0);
    store_tile();
    for (int k0 = 0; k0 < 2; k0++) {
        __syncthreads();
        if (k0 + 1 < 2) load_tile(k0 + 1);
        bf16x8 ah[4], al[4];
#pragma unroll
        for (int mt = 0; mt < 4; mt++) {
            int gmt = wave * 4 + mt;
            const unsigned short* ap = Sp1 + ((size_t)(k0 * 16 + gmt) * 2) * 512 + lane * 8;
            ah[mt] = *(const bf16x8*)ap;
            al[mt] = *(const bf16x8*)(ap + 512);
        }
#pragma unroll
        for (int nt = 0; nt < 4; nt++) {
            int nl = nt * 16 + lr;
            bf16x8 bh, bl;
#pragma unroll
            for (int j = 0; j < 8; j++) {
                unsigned u = Bt[(quad * 8 + j) * 65 + nl];
                union { unsigned uu; float ff; } c; c.uu = u;
                unsigned short hh = f2bf(c.ff);
                bh[j] = (short)hh;
                bl[j] = (short)f2bf(c.ff - bf2f(hh));
            }
#pragma unroll
            for (int mt = 0; mt < 4; mt++) {
                acc[mt][nt] = __builtin_amdgcn_mfma_f32_16x16x32_bf16(ah[mt], bh, acc[mt][nt], 0, 0, 0);
                acc[mt][nt] = __builtin_amdgcn_mfma_f32_16x16x32_bf16(ah[mt], bl, acc[mt][nt], 0, 0, 0);
                acc[mt][nt] = __builtin_amdgcn_mfma_f32_16x16x32_bf16(al[mt], bh, acc[mt][nt], 0, 0, 0);
            }
        }
        __syncthreads();
        if (k0 + 1 < 2) store_tile();
    }

    // epilogue: m=(i=gmt, a4=quad*4+r); k2 = l*16+i -> blocked store, us4 over mt
#pragma unroll
    for (int nt = 0; nt < 4; nt++) {
        int b = nt * 16 + lr;
#pragma unroll
        for (int r = 0; r < 4; r++) {
            int a4 = quad * 4 + r;
            us4 w;
#pragma unroll
            for (int mt = 0; mt < 4; mt++) w[mt] = f2h_bits(acc[mt][nt][r] * scale);
            size_t addr = (size_t)(o * 256 + m2 * 16 + a4) * 16384 +
                          (size_t)(l * 2 + (wave >> 1)) * 512 + b * 8 + (wave & 1) * 4;
            *(us4*)(t1 + addr) = w;
        }
    }
}

// ---- LDS-free f16 GEMM (G2: SM=2, G3: SM=3) ------------------------------
// B = f16 blocked panel [region][k/8][b·64][k%8]; frag = direct 16B load.
// A = f16 pack, hi only. 1 MFMA per (mt,nt). No __syncthreads anywhere.
template <int KT, int MT, int WS, int SM>
__global__ __launch_bounds__(256) void gemm_f16k(const unsigned short* __restrict__ Bp,
                                                 const unsigned short* __restrict__ Ap,
                                                 unsigned short* __restrict__ Co) {
    constexpr int NT = (WS == 0) ? 4 : 1;
    const int tid = threadIdx.x, lane = tid & 63, wave = tid >> 6;
    const int quad = lane >> 4, lr = lane & 15;
    const unsigned short* pb = Bp + (size_t)blockIdx.x * (KT * 2048);

    f32x4 acc[4][NT];
#pragma unroll
    for (int i = 0; i < 4; i++)
#pragma unroll
        for (int j = 0; j < NT; j++)
#pragma unroll
            for (int r = 0; r < 4; r++) acc[i][j][r] = 0.0f;

    f16x8 bf[2][NT];
    auto loadB = [&](int k0, int buf) {
#pragma unroll
        for (int nt = 0; nt < NT; nt++) {
            int b = (WS == 0) ? (nt * 16 + lr) : (wave * 16 + lr);
            bf[buf][nt] = *(const f16x8*)(pb + ((size_t)(k0 * 4 + quad) << 9) + b * 8);
        }
    };
    loadB(0, 0);
#pragma unroll
    for (int k0 = 0; k0 < KT; k0++) {
        if (k0 + 1 < KT) loadB(k0 + 1, (k0 + 1) & 1);
        f16x8 ah[4];
#pragma unroll
        for (int mt = 0; mt < 4; mt++) {
            int gmt = (WS == 0) ? (wave * 4 + mt) : mt;
            ah[mt] = *(const f16x8*)(Ap + ((size_t)(k0 * MT + gmt) * 2) * 512 + lane * 8);
        }
#pragma unroll
        for (int nt = 0; nt < NT; nt++)
#pragma unroll
            for (int mt = 0; mt < 4; mt++)
                acc[mt][nt] = __builtin_amdgcn_mfma_f32_16x16x32_f16(
                    ah[mt], bf[k0 & 1][nt], acc[mt][nt], 0, 0, 0);
    }

    if constexpr (SM == 2) {
        // region=(o,m2,a4); m=(j=gmt, L=quad*4+r); k3=o*16+j -> t2 panels
        const int o = blockIdx.x >> 8, m2 = (blockIdx.x >> 4) & 15, a4 = blockIdx.x & 15;
#pragma unroll
        for (int nt = 0; nt < NT; nt++) {
            int b = nt * 16 + lr;
#pragma unroll
            for (int r = 0; r < 4; r++) {
                int L = quad * 4 + r;
                us4 w;
#pragma unroll
                for (int mt = 0; mt < 4; mt++) w[mt] = f2h_bits(acc[mt][nt][r]);
                size_t addr = (size_t)(L * 256 + m2 * 16 + a4) * 4096 +
                              (size_t)(o * 2 + (wave >> 1)) * 512 + b * 8 + (wave & 1) * 4;
                *(us4*)(Co + addr) = w;
            }
        }
    } else {
        // SM==3: region=(L,m2,a4); m=(O2=mt, k2=quad*4+r); k4=m2*16+k2 -> t3 panels
        const int L = blockIdx.x >> 8, m2 = (blockIdx.x >> 4) & 15, a4 = blockIdx.x & 15;
        int b = wave * 16 + lr;
#pragma unroll
        for (int mt = 0; mt < 4; mt++) {
            us4 w;
#pragma unroll
            for (int r = 0; r < 4; r++) w[r] = f2h_bits(acc[mt][0][r]);
            size_t addr = (size_t)(mt * 256 + L * 16 + a4) * 16384 +
                          (size_t)(m2 * 2 + (quad >> 1)) * 512 + b * 8 + (quad & 1) * 4;
            *(us4*)(Co + addr) = w;
        }
    }
}

// ---- fused G4+G5: phase A LDS-free f16, phase B bf16 slabs ---------------
__global__ __launch_bounds__(256) void gemm_g45(const unsigned short* __restrict__ Bp,
                                                const unsigned short* __restrict__ Ap4,
                                                const unsigned short* __restrict__ Sp5,
                                                float* __restrict__ env, int A0,
                                                float inv) {
    __shared__ unsigned short S_h[16 * 264];
    __shared__ unsigned short S_l[16 * 264];
    const int tid = threadIdx.x, lane = tid & 63, wave = tid >> 6;
    const int quad = lane >> 4, lr = lane & 15;
    const int O2 = blockIdx.x >> 8, L = (blockIdx.x >> 4) & 15, a4 = blockIdx.x & 15;
    const unsigned short* pb = Bp + (size_t)blockIdx.x * 16384;

    f32x4 acc[4][4];
#pragma unroll
    for (int i = 0; i < 4; i++)
#pragma unroll
        for (int j = 0; j < 4; j++)
#pragma unroll
            for (int r = 0; r < 4; r++) acc[i][j][r] = 0.0f;

    f16x8 bf[2][4];
    auto loadB = [&](int k0, int buf) {
#pragma unroll
        for (int nt = 0; nt < 4; nt++) {
            int b = nt * 16 + lr;
            bf[buf][nt] = *(const f16x8*)(pb + ((size_t)(k0 * 4 + quad) << 9) + b * 8);
        }
    };
    loadB(0, 0);
#pragma unroll
    for (int k0 = 0; k0 < 8; k0++) {
        if (k0 + 1 < 8) loadB(k0 + 1, (k0 + 1) & 1);
        f16x8 ah[4];
#pragma unroll
        for (int mt = 0; mt < 4; mt++) {
            int gmt = wave * 4 + mt;
            ah[mt] = *(const f16x8*)(Ap4 + ((size_t)(k0 * 16 + gmt) * 2) * 512 + lane * 8);
        }
#pragma unroll
        for (int nt = 0; nt < 4; nt++)
#pragma unroll
            for (int mt = 0; mt < 4; mt++)
                acc[mt][nt] = __builtin_amdgcn_mfma_f32_16x16x32_f16(
                    ah[mt], bf[k0 & 1][nt], acc[mt][nt], 0, 0, 0);
    }

    // phase B: per mt, deposit slab (s = wave*4+mt; k-local = wave*64+b) then
    // contract k-chunks (s2,h): global chunk = (s2*4+mt)*2+h, local = s2*64+h*32
    f32x4 acc5;
#pragma unroll
    for (int r = 0; r < 4; r++) acc5[r] = 0.0f;
#pragma unroll
    for (int mt = 0; mt < 4; mt++) {
        if (mt) __syncthreads();
#pragma unroll
        for (int nt = 0; nt < 4; nt++)
#pragma unroll
            for (int r = 0; r < 4; r++) {
                unsigned u = split2(acc[mt][nt][r]);
                int addr = (quad * 4 + r) * 264 + wave * 64 + nt * 16 + lr;
                S_h[addr] = (unsigned short)u;
                S_l[addr] = (unsigned short)(u >> 16);
            }
        __syncthreads();
#pragma unroll
        for (int s2 = 0; s2 < 4; s2++)
#pragma unroll
            for (int h = 0; h < 2; h++) {
                int klocal = s2 * 64 + h * 32;
                bf16x8 th = *(const bf16x8*)(&S_h[lr * 264 + klocal + quad * 8]);
                bf16x8 tl = *(const bf16x8*)(&S_l[lr * 264 + klocal + quad * 8]);
                int kg = (s2 * 4 + mt) * 2 + h;
                const unsigned short* bp =
                    Sp5 + ((size_t)(kg * 4 + wave) * 2) * 512 + lane * 8;
                bf16x8 sh = *(const bf16x8*)bp;
                bf16x8 sl = *(const bf16x8*)(bp + 512);
                acc5 = __builtin_amdgcn_mfma_f32_16x16x32_bf16(th, sh, acc5, 0, 0, 0);
                acc5 = __builtin_amdgcn_mfma_f32_16x16x32_bf16(th, sl, acc5, 0, 0, 0);
                acc5 = __builtin_amdgcn_mfma_f32_16x16x32_bf16(tl, sh, acc5, 0, 0, 0);
            }
    }
    // row=M2=quad*4+r, col=B'=wave*16+lr -> envT[(L*64+O2*16+M2)][A0+a4][B']
#pragma unroll
    for (int r = 0; r < 4; r++)
        env[(size_t)(L * 64 + O2 * 16 + quad * 4 + r) * 4096 +
            (A0 + a4) * 64 + wave * 16 + lr] = acc5[r] * inv;
}

extern "C" void kernel_launch(void* const* d_in, const int* in_sizes, int n_in,
                              void* d_out, int out_size, void* d_ws, size_t ws_size,
                              hipStream_t stream) {
    const float* state = (const float*)d_in[0];   // [8,64,16,64]
    const float* layer = (const float*)d_in[1];   // [1,8,16,16,16,16]
    const float* oper  = (const float*)d_in[2];   // [8,4,16,16,4]
    float* out = (float*)d_out;

    const size_t need = (16777216ull + 16777216ull + 2 * 4194304ull) * 4ull +
                        (4 * 1048576ull + 65536ull) * 2ull + 4096ull;
    if (ws_size < need) {
        write_diag_kernel<<<1, 64, 0, stream>>>(out, (float)ws_size);
        return;
    }
    float* F    = (float*)d_ws;                    // t2 (u16, 32MB) + boundary scratch
    unsigned* P = (unsigned*)(F + 16777216);       // t1 + t3 (u16, 32MB each)
    float* envA = (float*)(P + 16777216);
    float* envB = envA + 4194304;
    unsigned short* Ap2 = (unsigned short*)(envB + 4194304);
    unsigned short* Ap4 = Ap2 + 1048576;
    unsigned short* Sp1 = Ap4 + 1048576;
    unsigned short* Sp5 = Sp1 + 1048576;
    unsigned short* Op3 = Sp5 + 1048576;
    float* sv = (float*)(Op3 + 65536);
    float* SCR = F;
    unsigned short* T1 = (unsigned short*)P;
    unsigned short* T3 = T1 + 16777216;
    unsigned short* T2 = (unsigned short*)F;

    prep_apack<<<256, 256, 0, stream>>>(layer, Ap2, Ap4);
    prep_spack1<<<256, 256, 0, stream>>>(state, Sp1);
    prep_spack5<<<256, 256, 0, stream>>>(state, Sp5);
    prep_opack3<<<16, 256, 0, stream>>>(oper, Op3);
    prep_sv<<<4, 256, 0, stream>>>(state, sv);

    // site 0 -> envB (exact fp32), envT tiled
    s0_g2<<<64, 256, 0, stream>>>(state, layer, SCR);
    s0_g3<<<256, 256, 0, stream>>>(SCR, oper, SCR + 16384);
    s0_g4<<<4096, 256, 0, stream>>>(SCR + 16384, layer, SCR + 81920);
    s0_env<<<16384, 256, 0, stream>>>(SCR + 81920, state, envB);

    for (int q = 1; q < 7; q++) {
        float* ein  = (q & 1) ? envB : envA;
        float* eout = (q & 1) ? envA : envB;
        float scl = (float)(1u << (16 + 2 * q));   // exact power of 2
        float inv = 1.0f / scl;
        for (int c = 0; c < 4; c++) {
            gemm_g1<<<1024, 256, 0, stream>>>(
                ein, Sp1 + (size_t)(q * 4 + c) * 32768, T1, scl);
            gemm_f16k<8, 16, 0, 2><<<1024, 256, 0, stream>>>(
                T1, Ap2 + (size_t)q * 131072, T2);
            gemm_f16k<2, 4, 1, 3><<<4096, 256, 0, stream>>>(
                T2, Op3 + (size_t)q * 8192, T3);
            gemm_g45<<<1024, 256, 0, stream>>>(
                T3, Ap4 + (size_t)q * 131072, Sp5 + (size_t)q * 131072, eout, c * 16, inv);
        }
    }

    // site 7: out = <env7 (envT, in envB), w>
    s7_c1<<<64, 256, 0, stream>>>(state, layer, SCR);
    s7_c2<<<256, 256, 0, stream>>>(SCR, oper, SCR + 16384);
    s7_c3<<<4096, 256, 0, stream>>>(SCR + 16384, layer, SCR + 81920);
    zero_out<<<1, 64, 0, stream>>>(out);
    s7_fused<<<1024, 256, 0, stream>>>(envB, SCR + 81920, sv, out);
}

// Round 12
// 1854.382 us; speedup vs baseline: 1.6061x; 1.0295x over previous
//
#include <hip/hip_runtime.h>

// ---------------------------------------------------------------------------
// <psi|U^dag O U|psi>, NQ=8, r=64 d=16 rl=16 ro=4.
// R12 = R11 + redesigned gemm_g45 phase B (was 35us of the 43us kernel):
//   wave w's phase-A acc holds s=4w..4w+3 = one k-quarter of G5. Each wave:
//   deposit own u32 split-pair slab [16 M2][68] (same-wave LDS, ordered by
//   s_waitcnt lgkmcnt(0), NO block barrier), contract its k-quarter over all
//   4 B'-tiles with 4 independent accumulators (ILP-4, hoistable Sp5 loads).
//   ONE __syncthreads + LDS reduce combines the 4 wave partials.
// Everything else identical to R11 (f16 intermediates + power-of-2 scaling,
// LDS-free G2/G3, bf16x3 G1, fp32 boundary chains).
// ---------------------------------------------------------------------------

typedef __attribute__((ext_vector_type(8))) short bf16x8;
typedef __attribute__((ext_vector_type(8))) _Float16 f16x8;
typedef __attribute__((ext_vector_type(4))) float f32x4;
typedef __attribute__((ext_vector_type(4))) unsigned short us4;

static __device__ __forceinline__ unsigned short f2bf(float x) {
    union { float f; unsigned u; } a; a.f = x;
    return (unsigned short)((a.u + 0x7FFF + ((a.u >> 16) & 1)) >> 16);
}
static __device__ __forceinline__ float bf2f(unsigned short h) {
    union { unsigned u; float f; } a; a.u = (unsigned)h << 16; return a.f;
}
static __device__ __forceinline__ unsigned split2(float x) {
    unsigned short h = f2bf(x);
    unsigned short l = f2bf(x - bf2f(h));
    return (unsigned)h | ((unsigned)l << 16);
}
static __device__ __forceinline__ unsigned short f2h_bits(float x) {
    union { _Float16 h; unsigned short u; } c; c.h = (_Float16)x; return c.u;
}
static __device__ __forceinline__ float h2f_bits(unsigned short u) {
    union { unsigned short u; _Float16 h; } c; c.u = u; return (float)c.h;
}

__global__ void write_diag_kernel(float* out, float v) {
    if (threadIdx.x == 0 && blockIdx.x == 0) out[0] = v;
}
__global__ void zero_out(float* o) {
    if (threadIdx.x == 0 && blockIdx.x == 0) o[0] = 0.0f;
}

// ---- A-operand fragment packs -------------------------------------------
__global__ void prep_apack(const float* __restrict__ layer,
                           unsigned short* __restrict__ Ap2,
                           unsigned short* __restrict__ Ap4) {
    int idx = blockIdx.x * 256 + threadIdx.x;   // 65536
    int q = idx >> 13, k0 = (idx >> 10) & 7, mt = (idx >> 6) & 15, lane = idx & 63;
    int quad = lane >> 4, r = lane & 15;
    unsigned short h2[8], l2[8], h4[8], l4[8];
#pragma unroll
    for (int j = 0; j < 8; j++) {
        int k = k0 * 32 + quad * 8 + j;
        int m = mt * 16 + r;
        float v2 = layer[(size_t)q * 65536 +
                         (size_t)((((k >> 4) * 16 + (m >> 4)) * 16 + (k & 15)) * 16 + (m & 15))];
        float v4 = layer[(size_t)q * 65536 +
                         (size_t)((((k >> 4) * 16 + (k & 15)) * 16 + (m >> 4)) * 16 + (m & 15))];
        h2[j] = f2h_bits(v2); l2[j] = f2h_bits(v2 - h2f_bits(h2[j]));
        h4[j] = f2h_bits(v4); l4[j] = f2h_bits(v4 - h2f_bits(h4[j]));
    }
    size_t base = ((size_t)((q * 8 + k0) * 16 + mt) * 2) * 512 + lane * 8;
    *(us4*)(Ap2 + base)       = *(us4*)&h2[0];
    *(us4*)(Ap2 + base + 4)   = *(us4*)&h2[4];
    *(us4*)(Ap2 + base + 512) = *(us4*)&l2[0];
    *(us4*)(Ap2 + base + 516) = *(us4*)&l2[4];
    *(us4*)(Ap4 + base)       = *(us4*)&h4[0];
    *(us4*)(Ap4 + base + 4)   = *(us4*)&h4[4];
    *(us4*)(Ap4 + base + 512) = *(us4*)&l4[0];
    *(us4*)(Ap4 + base + 516) = *(us4*)&l4[4];
}

__global__ void prep_spack1(const float* __restrict__ state,
                            unsigned short* __restrict__ Sp1) {
    int idx = blockIdx.x * 256 + threadIdx.x;   // 65536
    int q = idx >> 13, c = (idx >> 11) & 3, k0 = (idx >> 10) & 1,
        mt = (idx >> 6) & 15, lane = idx & 63;
    int quad = lane >> 4, lr = lane & 15;
    unsigned short h[8], l[8];
#pragma unroll
    for (int j = 0; j < 8; j++) {
        int k = k0 * 32 + quad * 8 + j;
        float v = state[(size_t)q * 65536 + (size_t)(k * 16 + mt) * 64 + c * 16 + lr];
        h[j] = f2bf(v); l[j] = f2bf(v - bf2f(h[j]));
    }
    size_t base = (size_t)(q * 4 + c) * 32768 + ((size_t)(k0 * 16 + mt) * 2) * 512 + lane * 8;
    *(us4*)(Sp1 + base)       = *(us4*)&h[0];
    *(us4*)(Sp1 + base + 4)   = *(us4*)&h[4];
    *(us4*)(Sp1 + base + 512) = *(us4*)&l[0];
    *(us4*)(Sp1 + base + 516) = *(us4*)&l[4];
}

__global__ void prep_spack5(const float* __restrict__ state,
                            unsigned short* __restrict__ Sp5) {
    int idx = blockIdx.x * 256 + threadIdx.x;   // 65536
    int q = idx >> 13, k0 = (idx >> 8) & 31, mt = (idx >> 6) & 3, lane = idx & 63;
    int quad = lane >> 4, lr = lane & 15;
    unsigned short h[8], l[8];
#pragma unroll
    for (int j = 0; j < 8; j++) {
        int k = k0 * 32 + quad * 8 + j;   // k = s*64+b
        int s = k >> 6, b = k & 63;
        float v = state[(size_t)q * 65536 + (size_t)(b * 16 + s) * 64 + mt * 16 + lr];
        h[j] = f2bf(v); l[j] = f2bf(v - bf2f(h[j]));
    }
    size_t base = (size_t)q * 131072 + ((size_t)(k0 * 4 + mt) * 2) * 512 + lane * 8;
    *(us4*)(Sp5 + base)       = *(us4*)&h[0];
    *(us4*)(Sp5 + base + 4)   = *(us4*)&h[4];
    *(us4*)(Sp5 + base + 512) = *(us4*)&l[0];
    *(us4*)(Sp5 + base + 516) = *(us4*)&l[4];
}

__global__ void prep_opack3(const float* __restrict__ oper,
                            unsigned short* __restrict__ Op3) {
    int idx = blockIdx.x * 256 + threadIdx.x;   // 4096
    int q = idx >> 9, k0 = (idx >> 8) & 1, mt = (idx >> 6) & 3, lane = idx & 63;
    int quad = lane >> 4, lr = lane & 15;
    unsigned short h[8], l[8];
#pragma unroll
    for (int j = 0; j < 8; j++) {
        int k = k0 * 32 + quad * 8 + j;
        int m = mt * 16 + lr;
        float v = oper[(size_t)q * 4096 + (size_t)(k * 16 + (m & 15)) * 4 + (m >> 4)];
        h[j] = f2h_bits(v); l[j] = f2h_bits(v - h2f_bits(h[j]));
    }
    size_t base = (size_t)q * 8192 + ((size_t)(k0 * 4 + mt) * 2) * 512 + lane * 8;
    *(us4*)(Op3 + base)       = *(us4*)&h[0];
    *(us4*)(Op3 + base + 4)   = *(us4*)&h[4];
    *(us4*)(Op3 + base + 512) = *(us4*)&l[0];
    *(us4*)(Op3 + base + 516) = *(us4*)&l[4];
}

// ---- site 0 (env0 = delta): env1 built by a cheap chain (fp32 exact) ----
__global__ void s0_g2(const float* __restrict__ state, const float* __restrict__ layer,
                      float* __restrict__ g2) {
    int t = blockIdx.x * 256 + threadIdx.x;          // 16384: [A][j][L]
    int A = t >> 8, j = (t >> 4) & 15, L = t & 15;
    float s = 0;
    for (int i = 0; i < 16; i++) s += state[i * 64 + A] * layer[(j * 16 + i) * 16 + L];
    g2[t] = s;
}
__global__ void s0_g3(const float* __restrict__ g2, const float* __restrict__ oper,
                      float* __restrict__ g3) {
    int t = blockIdx.x * 256 + threadIdx.x;          // 65536: [A][L][k][O]
    int A = t >> 10, L = (t >> 6) & 15, k = (t >> 2) & 15, O = t & 3;
    float s = 0;
    for (int j = 0; j < 16; j++) s += g2[A * 256 + j * 16 + L] * oper[(j * 16 + k) * 4 + O];
    g3[t] = s;
}
__global__ void s0_g4(const float* __restrict__ g3, const float* __restrict__ layer,
                      float* __restrict__ g4) {
    int t = blockIdx.x * 256 + threadIdx.x;          // 1048576: [A][L][O][s][M]
    int A = t >> 14, L = (t >> 10) & 15, O = (t >> 8) & 3, sp = (t >> 4) & 15, M = t & 15;
    float s = 0;
    for (int k = 0; k < 16; k++)
        s += g3[A * 1024 + L * 64 + k * 4 + O] * layer[(k * 16 + sp) * 16 + M];
    g4[t] = s;
}
__global__ void s0_env(const float* __restrict__ g4, const float* __restrict__ state,
                       float* __restrict__ env) {
    int t = blockIdx.x * 256 + threadIdx.x;          // 4194304
    int A = t >> 16, L = (t >> 12) & 15, O = (t >> 10) & 3, M = (t >> 6) & 15, B = t & 63;
    float s = 0;
    for (int sp = 0; sp < 16; sp++)
        s += g4[A * 16384 + L * 1024 + O * 256 + sp * 16 + M] * state[sp * 64 + B];
    env[(size_t)(L * 64 + O * 16 + M) * 4096 + A * 64 + B] = s;
}

// ---- site 7 chain (fp32) + fused dot ------------------------------------
__global__ void s7_c1(const float* __restrict__ state, const float* __restrict__ layer,
                      float* __restrict__ c1) {
    int t = blockIdx.x * 256 + threadIdx.x;          // 16384: [l][a][j]
    int l = t >> 10, a = (t >> 4) & 63, j = t & 15;
    float s = 0;
    for (int i = 0; i < 16; i++)
        s += state[7 * 65536 + (a * 16 + i) * 64] * layer[7 * 65536 + ((l * 16 + j) * 16 + i) * 16];
    c1[t] = s;
}
__global__ void s7_c2(const float* __restrict__ c1, const float* __restrict__ oper,
                      float* __restrict__ c2) {
    int t = blockIdx.x * 256 + threadIdx.x;          // 65536: [o][l][a][k]
    int o = t >> 14, l = (t >> 10) & 15, a = (t >> 4) & 63, k = t & 15;
    float s = 0;
    for (int j = 0; j < 16; j++)
        s += c1[l * 1024 + a * 16 + j] * oper[7 * 4096 + ((o * 16 + j) * 16 + k) * 4];
    c2[t] = s;
}
__global__ void s7_c3(const float* __restrict__ c2, const float* __restrict__ layer,
                      float* __restrict__ c3) {
    int t = blockIdx.x * 256 + threadIdx.x;          // 1048576: [m][o][l][a][s]
    int m = t >> 16, o = (t >> 14) & 3, l = (t >> 10) & 15, a = (t >> 4) & 63, sp = t & 15;
    float s = 0;
    for (int k = 0; k < 16; k++)
        s += c2[o * 16384 + l * 1024 + a * 16 + k] *
             layer[7 * 65536 + ((m * 16 + k) * 16 + sp) * 16];
    c3[t] = s;
}
__global__ void prep_sv(const float* __restrict__ state, float* __restrict__ sv) {
    int t = blockIdx.x * 256 + threadIdx.x;          // 1024: [b][sp]
    sv[t] = state[7 * 65536 + t * 64];
}
__global__ __launch_bounds__(256) void s7_fused(const float* __restrict__ env,
                                                const float* __restrict__ c3,
                                                const float* __restrict__ sv,
                                                float* __restrict__ out) {
    __shared__ float c3s[1024], svs[1024], red[256];
    int t = threadIdx.x;
    int n0 = blockIdx.x * 64;            // region=(l,o,m)
    int l = n0 >> 12, o = (n0 >> 10) & 3, m = (n0 >> 6) & 15;
    const float* c3b = c3 + m * 65536 + o * 16384 + l * 1024;   // [a][sp]
    const float* eb  = env + (size_t)blockIdx.x * 4096;         // [a][b]
    for (int i = t; i < 1024; i += 256) { c3s[i] = c3b[i]; svs[i] = sv[i]; }
    __syncthreads();
    float s = 0;
    int b = t & 63, ag = t >> 6;
#pragma unroll
    for (int g = 0; g < 16; g++) {
        int a = ag * 16 + g;
        float e = eb[a * 64 + b];
        float w = 0;
#pragma unroll
        for (int sp = 0; sp < 16; sp++) w += c3s[a * 16 + sp] * svs[b * 16 + sp];
        s += e * w;
    }
    red[t] = s; __syncthreads();
    for (int off = 128; off; off >>= 1) { if (t < off) red[t] += red[t + off]; __syncthreads(); }
    if (t == 0) atomicAdd(out, red[0]);
}

// ---- G1: env (fp32, LDS bf16x3) x Sp1 -> t1 f16 blocked panels -----------
__global__ __launch_bounds__(256) void gemm_g1(const float* __restrict__ envp,
                                               const unsigned short* __restrict__ Sp1,
                                               unsigned short* __restrict__ t1,
                                               float scale) {
    __shared__ unsigned Bt[32 * 65];
    const int tid = threadIdx.x, lane = tid & 63, wave = tid >> 6;
    const int quad = lane >> 4, lr = lane & 15;
    const int l = blockIdx.x >> 6, o = (blockIdx.x >> 4) & 3, m2 = blockIdx.x & 15;

    f32x4 acc[4][4];
#pragma unroll
    for (int i = 0; i < 4; i++)
#pragma unroll
        for (int j = 0; j < 4; j++)
#pragma unroll
            for (int r = 0; r < 4; r++) acc[i][j][r] = 0.0f;

    const unsigned* Bv = (const unsigned*)envp + (size_t)blockIdx.x * 4096;
    uint4 ur[2];
    auto load_tile = [&](int k0) {
        const uint4* src = (const uint4*)(Bv + k0 * 2048);
        ur[0] = src[tid];
        ur[1] = src[256 + tid];
    };
    auto store_tile = [&]() {
#pragma unroll
        for (int v = 0; v < 2; v++) {
            int e = v * 256 + tid;
            unsigned* p = &Bt[(e >> 4) * 65 + (e & 15) * 4];
            p[0] = ur[v].x; p[1] = ur[v].y; p[2] = ur[v].z; p[3] = ur[v].w;
        }
    };

    load_tile(0);
    store_tile();
    for (int k0 = 0; k0 < 2; k0++) {
        __syncthreads();
        if (k0 + 1 < 2) load_tile(k0 + 1);
        bf16x8 ah[4], al[4];
#pragma unroll
        for (int mt = 0; mt < 4; mt++) {
            int gmt = wave * 4 + mt;
            const unsigned short* ap = Sp1 + ((size_t)(k0 * 16 + gmt) * 2) * 512 + lane * 8;
            ah[mt] = *(const bf16x8*)ap;
            al[mt] = *(const bf16x8*)(ap + 512);
        }
#pragma unroll
        for (int nt = 0; nt < 4; nt++) {
            int nl = nt * 16 + lr;
            bf16x8 bh, bl;
#pragma unroll
            for (int j = 0; j < 8; j++) {
                unsigned u = Bt[(quad * 8 + j) * 65 + nl];
                union { unsigned uu; float ff; } c; c.uu = u;
                unsigned short hh = f2bf(c.ff);
                bh[j] = (short)hh;
                bl[j] = (short)f2bf(c.ff - bf2f(hh));
            }
#pragma unroll
            for (int mt = 0; mt < 4; mt++) {
                acc[mt][nt] = __builtin_amdgcn_mfma_f32_16x16x32_bf16(ah[mt], bh, acc[mt][nt], 0, 0, 0);
                acc[mt][nt] = __builtin_amdgcn_mfma_f32_16x16x32_bf16(ah[mt], bl, acc[mt][nt], 0, 0, 0);
                acc[mt][nt] = __builtin_amdgcn_mfma_f32_16x16x32_bf16(al[mt], bh, acc[mt][nt], 0, 0, 0);
            }
        }
        __syncthreads();
        if (k0 + 1 < 2) store_tile();
    }

#pragma unroll
    for (int nt = 0; nt < 4; nt++) {
        int b = nt * 16 + lr;
#pragma unroll
        for (int r = 0; r < 4; r++) {
            int a4 = quad * 4 + r;
            us4 w;
#pragma unroll
            for (int mt = 0; mt < 4; mt++) w[mt] = f2h_bits(acc[mt][nt][r] * scale);
            size_t addr = (size_t)(o * 256 + m2 * 16 + a4) * 16384 +
                          (size_t)(l * 2 + (wave >> 1)) * 512 + b * 8 + (wave & 1) * 4;
            *(us4*)(t1 + addr) = w;
        }
    }
}

// ---- LDS-free f16 GEMM (G2: SM=2, G3: SM=3) ------------------------------
template <int KT, int MT, int WS, int SM>
__global__ __launch_bounds__(256) void gemm_f16k(const unsigned short* __restrict__ Bp,
                                                 const unsigned short* __restrict__ Ap,
                                                 unsigned short* __restrict__ Co) {
    constexpr int NT = (WS == 0) ? 4 : 1;
    const int tid = threadIdx.x, lane = tid & 63, wave = tid >> 6;
    const int quad = lane >> 4, lr = lane & 15;
    const unsigned short* pb = Bp + (size_t)blockIdx.x * (KT * 2048);

    f32x4 acc[4][NT];
#pragma unroll
    for (int i = 0; i < 4; i++)
#pragma unroll
        for (int j = 0; j < NT; j++)
#pragma unroll
            for (int r = 0; r < 4; r++) acc[i][j][r] = 0.0f;

    f16x8 bf[2][NT];
    auto loadB = [&](int k0, int buf) {
#pragma unroll
        for (int nt = 0; nt < NT; nt++) {
            int b = (WS == 0) ? (nt * 16 + lr) : (wave * 16 + lr);
            bf[buf][nt] = *(const f16x8*)(pb + ((size_t)(k0 * 4 + quad) << 9) + b * 8);
        }
    };
    loadB(0, 0);
#pragma unroll
    for (int k0 = 0; k0 < KT; k0++) {
        if (k0 + 1 < KT) loadB(k0 + 1, (k0 + 1) & 1);
        f16x8 ah[4];
#pragma unroll
        for (int mt = 0; mt < 4; mt++) {
            int gmt = (WS == 0) ? (wave * 4 + mt) : mt;
            ah[mt] = *(const f16x8*)(Ap + ((size_t)(k0 * MT + gmt) * 2) * 512 + lane * 8);
        }
#pragma unroll
        for (int nt = 0; nt < NT; nt++)
#pragma unroll
            for (int mt = 0; mt < 4; mt++)
                acc[mt][nt] = __builtin_amdgcn_mfma_f32_16x16x32_f16(
                    ah[mt], bf[k0 & 1][nt], acc[mt][nt], 0, 0, 0);
    }

    if constexpr (SM == 2) {
        const int o = blockIdx.x >> 8, m2 = (blockIdx.x >> 4) & 15, a4 = blockIdx.x & 15;
#pragma unroll
        for (int nt = 0; nt < NT; nt++) {
            int b = nt * 16 + lr;
#pragma unroll
            for (int r = 0; r < 4; r++) {
                int L = quad * 4 + r;
                us4 w;
#pragma unroll
                for (int mt = 0; mt < 4; mt++) w[mt] = f2h_bits(acc[mt][nt][r]);
                size_t addr = (size_t)(L * 256 + m2 * 16 + a4) * 4096 +
                              (size_t)(o * 2 + (wave >> 1)) * 512 + b * 8 + (wave & 1) * 4;
                *(us4*)(Co + addr) = w;
            }
        }
    } else {
        const int L = blockIdx.x >> 8, m2 = (blockIdx.x >> 4) & 15, a4 = blockIdx.x & 15;
        int b = wave * 16 + lr;
#pragma unroll
        for (int mt = 0; mt < 4; mt++) {
            us4 w;
#pragma unroll
            for (int r = 0; r < 4; r++) w[r] = f2h_bits(acc[mt][0][r]);
            size_t addr = (size_t)(mt * 256 + L * 16 + a4) * 16384 +
                          (size_t)(m2 * 2 + (quad >> 1)) * 512 + b * 8 + (quad & 1) * 4;
            *(us4*)(Co + addr) = w;
        }
    }
}

// ---- fused G4+G5: phase A LDS-free f16; phase B per-wave barrier-free ----
__global__ __launch_bounds__(256) void gemm_g45(const unsigned short* __restrict__ Bp,
                                                const unsigned short* __restrict__ Ap4,
                                                const unsigned short* __restrict__ Sp5,
                                                float* __restrict__ env, int A0,
                                                float inv) {
    __shared__ unsigned SL[4 * 16 * 68];   // per-wave u32 slab / reduce buffer
    const int tid = threadIdx.x, lane = tid & 63, wave = tid >> 6;
    const int quad = lane >> 4, lr = lane & 15;
    const int O2 = blockIdx.x >> 8, L = (blockIdx.x >> 4) & 15, a4 = blockIdx.x & 15;
    const unsigned short* pb = Bp + (size_t)blockIdx.x * 16384;

    f32x4 acc[4][4];
#pragma unroll
    for (int i = 0; i < 4; i++)
#pragma unroll
        for (int j = 0; j < 4; j++)
#pragma unroll
            for (int r = 0; r < 4; r++) acc[i][j][r] = 0.0f;

    f16x8 bf[2][4];
    auto loadB = [&](int k0, int buf) {
#pragma unroll
        for (int nt = 0; nt < 4; nt++) {
            int b = nt * 16 + lr;
            bf[buf][nt] = *(const f16x8*)(pb + ((size_t)(k0 * 4 + quad) << 9) + b * 8);
        }
    };
    loadB(0, 0);
#pragma unroll
    for (int k0 = 0; k0 < 8; k0++) {
        if (k0 + 1 < 8) loadB(k0 + 1, (k0 + 1) & 1);
        f16x8 ah[4];
#pragma unroll
        for (int mt = 0; mt < 4; mt++) {
            int gmt = wave * 4 + mt;
            ah[mt] = *(const f16x8*)(Ap4 + ((size_t)(k0 * 16 + gmt) * 2) * 512 + lane * 8);
        }
#pragma unroll
        for (int nt = 0; nt < 4; nt++)
#pragma unroll
            for (int mt = 0; mt < 4; mt++)
                acc[mt][nt] = __builtin_amdgcn_mfma_f32_16x16x32_f16(
                    ah[mt], bf[k0 & 1][nt], acc[mt][nt], 0, 0, 0);
    }

    // phase B: per-wave k-quarter (s = 4*wave..4*wave+3), barrier-free.
    unsigned* myslab = SL + wave * (16 * 68);
    f32x4 acc5[4];
#pragma unroll
    for (int nt = 0; nt < 4; nt++)
#pragma unroll
        for (int r = 0; r < 4; r++) acc5[nt][r] = 0.0f;

#pragma unroll
    for (int mtp = 0; mtp < 4; mtp++) {
        int s = wave * 4 + mtp;
        // deposit own slab [M2=16][b=64 pad 68] (u32 split-pair)
#pragma unroll
        for (int nt = 0; nt < 4; nt++)
#pragma unroll
            for (int r = 0; r < 4; r++)
                myslab[(quad * 4 + r) * 68 + nt * 16 + lr] = split2(acc[mtp][nt][r]);
        // same-wave cross-lane LDS dependency: drain LDS pipe, pin ordering
        asm volatile("s_waitcnt lgkmcnt(0)" ::: "memory");
#pragma unroll
        for (int h = 0; h < 2; h++) {
            const unsigned* sp = &myslab[lr * 68 + h * 32 + quad * 8];
            uint4 u0 = *(const uint4*)sp;
            uint4 u1 = *(const uint4*)(sp + 4);
            bf16x8 th, tl;
            th[0] = (short)(u0.x & 0xffff); tl[0] = (short)(u0.x >> 16);
            th[1] = (short)(u0.y & 0xffff); tl[1] = (short)(u0.y >> 16);
            th[2] = (short)(u0.z & 0xffff); tl[2] = (short)(u0.z >> 16);
            th[3] = (short)(u0.w & 0xffff); tl[3] = (short)(u0.w >> 16);
            th[4] = (short)(u1.x & 0xffff); tl[4] = (short)(u1.x >> 16);
            th[5] = (short)(u1.y & 0xffff); tl[5] = (short)(u1.y >> 16);
            th[6] = (short)(u1.z & 0xffff); tl[6] = (short)(u1.z >> 16);
            th[7] = (short)(u1.w & 0xffff); tl[7] = (short)(u1.w >> 16);
            int kg = s * 2 + h;
#pragma unroll
            for (int nt = 0; nt < 4; nt++) {
                const unsigned short* bp =
                    Sp5 + ((size_t)(kg * 4 + nt) * 2) * 512 + lane * 8;
                bf16x8 sh = *(const bf16x8*)bp;
                bf16x8 sl = *(const bf16x8*)(bp + 512);
                acc5[nt] = __builtin_amdgcn_mfma_f32_16x16x32_bf16(th, sh, acc5[nt], 0, 0, 0);
                acc5[nt] = __builtin_amdgcn_mfma_f32_16x16x32_bf16(th, sl, acc5[nt], 0, 0, 0);
                acc5[nt] = __builtin_amdgcn_mfma_f32_16x16x32_bf16(tl, sh, acc5[nt], 0, 0, 0);
            }
        }
    }

    // cross-wave reduce: one barrier, float view of SL
    __syncthreads();
    float* red = (float*)SL;
#pragma unroll
    for (int nt = 0; nt < 4; nt++)
#pragma unroll
        for (int r = 0; r < 4; r++)
            red[wave * 1088 + (quad * 4 + r) * 68 + nt * 16 + lr] = acc5[nt][r];
    __syncthreads();
#pragma unroll
    for (int r = 0; r < 4; r++) {
        int M2 = quad * 4 + r, Bc = wave * 16 + lr;
        float v = red[M2 * 68 + Bc] + red[1088 + M2 * 68 + Bc] +
                  red[2176 + M2 * 68 + Bc] + red[3264 + M2 * 68 + Bc];
        env[(size_t)(L * 64 + O2 * 16 + M2) * 4096 + (A0 + a4) * 64 + Bc] = v * inv;
    }
}

extern "C" void kernel_launch(void* const* d_in, const int* in_sizes, int n_in,
                              void* d_out, int out_size, void* d_ws, size_t ws_size,
                              hipStream_t stream) {
    const float* state = (const float*)d_in[0];   // [8,64,16,64]
    const float* layer = (const float*)d_in[1];   // [1,8,16,16,16,16]
    const float* oper  = (const float*)d_in[2];   // [8,4,16,16,4]
    float* out = (float*)d_out;

    const size_t need = (16777216ull + 16777216ull + 2 * 4194304ull) * 4ull +
                        (4 * 1048576ull + 65536ull) * 2ull + 4096ull;
    if (ws_size < need) {
        write_diag_kernel<<<1, 64, 0, stream>>>(out, (float)ws_size);
        return;
    }
    float* F    = (float*)d_ws;
    unsigned* P = (unsigned*)(F + 16777216);
    float* envA = (float*)(P + 16777216);
    float* envB = envA + 4194304;
    unsigned short* Ap2 = (unsigned short*)(envB + 4194304);
    unsigned short* Ap4 = Ap2 + 1048576;
    unsigned short* Sp1 = Ap4 + 1048576;
    unsigned short* Sp5 = Sp1 + 1048576;
    unsigned short* Op3 = Sp5 + 1048576;
    float* sv = (float*)(Op3 + 65536);
    float* SCR = F;
    unsigned short* T1 = (unsigned short*)P;
    unsigned short* T3 = T1 + 16777216;
    unsigned short* T2 = (unsigned short*)F;

    prep_apack<<<256, 256, 0, stream>>>(layer, Ap2, Ap4);
    prep_spack1<<<256, 256, 0, stream>>>(state, Sp1);
    prep_spack5<<<256, 256, 0, stream>>>(state, Sp5);
    prep_opack3<<<16, 256, 0, stream>>>(oper, Op3);
    prep_sv<<<4, 256, 0, stream>>>(state, sv);

    // site 0 -> envB (exact fp32), envT tiled
    s0_g2<<<64, 256, 0, stream>>>(state, layer, SCR);
    s0_g3<<<256, 256, 0, stream>>>(SCR, oper, SCR + 16384);
    s0_g4<<<4096, 256, 0, stream>>>(SCR + 16384, layer, SCR + 81920);
    s0_env<<<16384, 256, 0, stream>>>(SCR + 81920, state, envB);

    for (int q = 1; q < 7; q++) {
        float* ein  = (q & 1) ? envB : envA;
        float* eout = (q & 1) ? envA : envB;
        float scl = (float)(1u << (16 + 2 * q));   // exact power of 2
        float inv = 1.0f / scl;
        for (int c = 0; c < 4; c++) {
            gemm_g1<<<1024, 256, 0, stream>>>(
                ein, Sp1 + (size_t)(q * 4 + c) * 32768, T1, scl);
            gemm_f16k<8, 16, 0, 2><<<1024, 256, 0, stream>>>(
                T1, Ap2 + (size_t)q * 131072, T2);
            gemm_f16k<2, 4, 1, 3><<<4096, 256, 0, stream>>>(
                T2, Op3 + (size_t)q * 8192, T3);
            gemm_g45<<<1024, 256, 0, stream>>>(
                T3, Ap4 + (size_t)q * 131072, Sp5 + (size_t)q * 131072, eout, c * 16, inv);
        }
    }

    // site 7: out = <env7 (envT, in envB), w>
    s7_c1<<<64, 256, 0, stream>>>(state, layer, SCR);
    s7_c2<<<256, 256, 0, stream>>>(SCR, oper, SCR + 16384);
    s7_c3<<<4096, 256, 0, stream>>>(SCR + 16384, layer, SCR + 81920);
    zero_out<<<1, 64, 0, stream>>>(out);
    s7_fused<<<1024, 256, 0, stream>>>(envB, SCR + 81920, sv, out);
}